// Round 3
// baseline (137.693 us; speedup 1.0000x reference)
//
#include <hip/hip_runtime.h>

// Problem constants
#define B_    16
#define N1_   32
#define NL_   256
#define DM_   16
#define A_    2
#define DK_   8
#define DV_   8
#define DOUT_ 16

#define NBN   (B_ * N1_)                  // 512 blocks
#define PROJ_ELEMS (NBN * NL_ * DOUT_)    // 2097152

// LDS layout (float offsets). QP padded to stride 17 (conflict-free strided reads).
#define QP_OFF   0                        // 256*17 = 4352
#define KP_OFF   4352                     // 256*16 = 4096 (16B-aligned: 4352*4=17408)
#define VP_OFF   8448                     // 4096   (8448*4=33792, 16B-aligned)
#define WQ_OFF   12544                    // 256
#define WK_OFF   12800                    // 256
#define WV_OFF   13056                    // 256
#define WO_OFF   13312                    // 256
#define LDS_FLOATS 13568                  // 54272 B = 53 KB
// Epilogue aliases (QP/KP/VP dead by then; weights region untouched):
#define EMBA_OFF 0                        // 256*17 = 4352
#define EMBB_OFF 4352                     // 256*17 = 4352 (ends 8704 < WQ_OFF)

__global__ __launch_bounds__(256, 2)
void mha_relu_kernel(const float* __restrict__ Q,
                     const float* __restrict__ K,
                     const float* __restrict__ V,
                     const float* __restrict__ Wq,
                     const float* __restrict__ Wk,
                     const float* __restrict__ Wv,
                     const float* __restrict__ Wo,
                     float* __restrict__ proj_out,
                     float* __restrict__ attn_out)
{
    __shared__ float lds[LDS_FLOATS];

    const int tid = threadIdx.x;
    const int bn  = blockIdx.x;
    const int w   = tid >> 6;             // wave id 0..3 -> z-range [64w, 64w+64)
    const int l   = tid & 63;             // lane; owns rows 64j+l, j=0..3

    // ---- weights -> LDS (each array is exactly 256 floats) ----
    lds[WQ_OFF + tid] = Wq[tid];
    lds[WK_OFF + tid] = Wk[tid];
    lds[WV_OFF + tid] = Wv[tid];
    lds[WO_OFF + tid] = Wo[tid];
    __syncthreads();

    const size_t inoff = (size_t)bn * NL_ * DM_;

    // ---- phase 1: per-row projections (thread t computes row t) ----
    {
        float rowbuf[16], acc[16];

        // Q row -> QP (padded stride 17)
        {
            const float4* p = (const float4*)(Q + inoff + (size_t)tid * DM_);
            #pragma unroll
            for (int i = 0; i < 4; ++i) {
                float4 t = p[i];
                rowbuf[4*i+0] = t.x; rowbuf[4*i+1] = t.y;
                rowbuf[4*i+2] = t.z; rowbuf[4*i+3] = t.w;
            }
            #pragma unroll
            for (int c = 0; c < 16; ++c) acc[c] = 0.f;
            #pragma unroll
            for (int i = 0; i < 16; ++i) {
                const float qi = rowbuf[i];
                #pragma unroll
                for (int c = 0; c < 16; ++c) acc[c] += qi * lds[WQ_OFF + i*16 + c];
            }
            #pragma unroll
            for (int c = 0; c < 16; ++c) lds[QP_OFF + tid*17 + c] = acc[c];
        }
        // K row -> KP (stride 16, 16B-aligned rows for broadcast float4 reads)
        {
            const float4* p = (const float4*)(K + inoff + (size_t)tid * DM_);
            #pragma unroll
            for (int i = 0; i < 4; ++i) {
                float4 t = p[i];
                rowbuf[4*i+0] = t.x; rowbuf[4*i+1] = t.y;
                rowbuf[4*i+2] = t.z; rowbuf[4*i+3] = t.w;
            }
            #pragma unroll
            for (int c = 0; c < 16; ++c) acc[c] = 0.f;
            #pragma unroll
            for (int i = 0; i < 16; ++i) {
                const float ki = rowbuf[i];
                #pragma unroll
                for (int c = 0; c < 16; ++c) acc[c] += ki * lds[WK_OFF + i*16 + c];
            }
            #pragma unroll
            for (int c = 0; c < 16; ++c) lds[KP_OFF + tid*16 + c] = acc[c];
        }
        // V row -> VP
        {
            const float4* p = (const float4*)(V + inoff + (size_t)tid * DM_);
            #pragma unroll
            for (int i = 0; i < 4; ++i) {
                float4 t = p[i];
                rowbuf[4*i+0] = t.x; rowbuf[4*i+1] = t.y;
                rowbuf[4*i+2] = t.z; rowbuf[4*i+3] = t.w;
            }
            #pragma unroll
            for (int c = 0; c < 16; ++c) acc[c] = 0.f;
            #pragma unroll
            for (int i = 0; i < 16; ++i) {
                const float vi = rowbuf[i];
                #pragma unroll
                for (int c = 0; c < 16; ++c) acc[c] += vi * lds[WV_OFF + i*16 + c];
            }
            #pragma unroll
            for (int c = 0; c < 16; ++c) lds[VP_OFF + tid*16 + c] = acc[c];
        }
    }
    __syncthreads();

    // ---- load this lane's 4 Qp rows into registers (stride-17: 2-way, free) ----
    float Qp[4][16];
    #pragma unroll
    for (int j = 0; j < 4; ++j) {
        const int row = 64*j + l;
        #pragma unroll
        for (int c = 0; c < 16; ++c) Qp[j][c] = lds[QP_OFF + row*17 + c];
    }

    // ---- main loop: wave w covers z in [64w, 64w+64) for all 256 rows ----
    float emb[4][16];
    #pragma unroll
    for (int j = 0; j < 4; ++j)
        #pragma unroll
        for (int c = 0; c < 16; ++c) emb[j][c] = 0.f;

    const int z0 = w * 64;
    float* aout = attn_out + (size_t)bn * NL_ * NL_;

    #pragma unroll 1
    for (int zt = 0; zt < 16; ++zt) {     // 4 z per iteration
        float at4[4][4];
        #pragma unroll
        for (int dz = 0; dz < 4; ++dz) {
            const int z = z0 + zt*4 + dz;
            // broadcast reads (uniform address; 128 B feeds 128 FMAs)
            const float4 k0 = *(const float4*)&lds[KP_OFF + z*16 + 0];
            const float4 k1 = *(const float4*)&lds[KP_OFF + z*16 + 4];
            const float4 k2 = *(const float4*)&lds[KP_OFF + z*16 + 8];
            const float4 k3 = *(const float4*)&lds[KP_OFF + z*16 + 12];
            const float4 v0 = *(const float4*)&lds[VP_OFF + z*16 + 0];
            const float4 v1 = *(const float4*)&lds[VP_OFF + z*16 + 4];
            const float4 v2 = *(const float4*)&lds[VP_OFF + z*16 + 8];
            const float4 v3 = *(const float4*)&lds[VP_OFF + z*16 + 12];
            #pragma unroll
            for (int j = 0; j < 4; ++j) {
                float s0 = Qp[j][0]*k0.x + Qp[j][1]*k0.y + Qp[j][2]*k0.z + Qp[j][3]*k0.w
                         + Qp[j][4]*k1.x + Qp[j][5]*k1.y + Qp[j][6]*k1.z + Qp[j][7]*k1.w;
                float s1 = Qp[j][8]*k2.x + Qp[j][9]*k2.y + Qp[j][10]*k2.z + Qp[j][11]*k2.w
                         + Qp[j][12]*k3.x + Qp[j][13]*k3.y + Qp[j][14]*k3.z + Qp[j][15]*k3.w;
                s0 = fmaxf(s0, 0.f);
                s1 = fmaxf(s1, 0.f);
                at4[j][dz] = 0.5f * (s0 + s1);
                emb[j][0]  += s0*v0.x; emb[j][1]  += s0*v0.y; emb[j][2]  += s0*v0.z; emb[j][3]  += s0*v0.w;
                emb[j][4]  += s0*v1.x; emb[j][5]  += s0*v1.y; emb[j][6]  += s0*v1.z; emb[j][7]  += s0*v1.w;
                emb[j][8]  += s1*v2.x; emb[j][9]  += s1*v2.y; emb[j][10] += s1*v2.z; emb[j][11] += s1*v2.w;
                emb[j][12] += s1*v3.x; emb[j][13] += s1*v3.y; emb[j][14] += s1*v3.z; emb[j][15] += s1*v3.w;
            }
        }
        // direct global stores: 16 B per lane, rows complete in L2 over zt steps
        #pragma unroll
        for (int j = 0; j < 4; ++j) {
            *(float4*)&aout[(size_t)(64*j + l) * NL_ + z0 + zt*4] =
                make_float4(at4[j][0], at4[j][1], at4[j][2], at4[j][3]);
        }
    }

    // ---- cross-wave emb reduction (z-split partials) ----
    __syncthreads();                      // all main loops done; QP/KP/VP dead
    if (w == 0) {
        #pragma unroll
        for (int j = 0; j < 4; ++j)
            #pragma unroll
            for (int c = 0; c < 16; ++c) lds[EMBA_OFF + (64*j+l)*17 + c] = emb[j][c];
    } else if (w == 1) {
        #pragma unroll
        for (int j = 0; j < 4; ++j)
            #pragma unroll
            for (int c = 0; c < 16; ++c) lds[EMBB_OFF + (64*j+l)*17 + c] = emb[j][c];
    }
    __syncthreads();
    if (w == 2) {
        #pragma unroll
        for (int j = 0; j < 4; ++j)
            #pragma unroll
            for (int c = 0; c < 16; ++c) lds[EMBA_OFF + (64*j+l)*17 + c] += emb[j][c];
    } else if (w == 3) {
        #pragma unroll
        for (int j = 0; j < 4; ++j)
            #pragma unroll
            for (int c = 0; c < 16; ++c) lds[EMBB_OFF + (64*j+l)*17 + c] += emb[j][c];
    }
    __syncthreads();

    // ---- output projection: thread t owns row t ----
    float e[16];
    #pragma unroll
    for (int c = 0; c < 16; ++c)
        e[c] = lds[EMBA_OFF + tid*17 + c] + lds[EMBB_OFF + tid*17 + c];

    float pr[16];
    #pragma unroll
    for (int o = 0; o < 16; ++o) pr[o] = 0.f;
    #pragma unroll
    for (int a = 0; a < 2; ++a) {
        #pragma unroll
        for (int m = 0; m < 8; ++m) {
            const float ev = e[a*8 + m];
            #pragma unroll
            for (int o = 0; o < 16; ++o) pr[o] += ev * lds[WO_OFF + m*32 + a*16 + o];
        }
    }
    float4* po = (float4*)(proj_out + (size_t)bn * NL_ * DOUT_ + (size_t)tid * DOUT_);
    po[0] = make_float4(pr[0],  pr[1],  pr[2],  pr[3]);
    po[1] = make_float4(pr[4],  pr[5],  pr[6],  pr[7]);
    po[2] = make_float4(pr[8],  pr[9],  pr[10], pr[11]);
    po[3] = make_float4(pr[12], pr[13], pr[14], pr[15]);
}

extern "C" void kernel_launch(void* const* d_in, const int* in_sizes, int n_in,
                              void* d_out, int out_size, void* d_ws, size_t ws_size,
                              hipStream_t stream) {
    const float* Q  = (const float*)d_in[0];
    const float* K  = (const float*)d_in[1];
    const float* V  = (const float*)d_in[2];
    const float* Wq = (const float*)d_in[3];
    const float* Wk = (const float*)d_in[4];
    const float* Wv = (const float*)d_in[5];
    const float* Wo = (const float*)d_in[6];

    float* proj = (float*)d_out;
    float* attn = (float*)d_out + PROJ_ELEMS;

    mha_relu_kernel<<<NBN, 256, 0, stream>>>(Q, K, V, Wq, Wk, Wv, Wo, proj, attn);
}

// Round 6
// 135.869 us; speedup vs baseline: 1.0134x; 1.0134x over previous
//
#include <hip/hip_runtime.h>

// Problem constants
#define B_    16
#define N1_   32
#define NL_   256
#define DM_   16
#define A_    2
#define DK_   8
#define DV_   8
#define DOUT_ 16

#define NBN   (B_ * N1_)                  // 512 blocks
#define PROJ_ELEMS (NBN * NL_ * DOUT_)    // 2097152

// LDS layout (float offsets). QP padded to stride 17 (conflict-free strided reads).
#define QP_OFF   0                        // 256*17 = 4352
#define KP_OFF   4352                     // 256*16 = 4096 (16B-aligned)
#define VP_OFF   8448                     // 4096
#define WQ_OFF   12544                    // 256
#define WK_OFF   12800                    // 256
#define WV_OFF   13056                    // 256
#define WO_OFF   13312                    // 256
#define LDS_FLOATS 13568                  // 54272 B
// Epilogue aliases (QP/KP/VP dead by then; weights region untouched):
#define EMBA_OFF 0
#define EMBB_OFF 4352

__global__ __launch_bounds__(256, 2)
void mha_relu_kernel(const float* __restrict__ Q,
                     const float* __restrict__ K,
                     const float* __restrict__ V,
                     const float* __restrict__ Wq,
                     const float* __restrict__ Wk,
                     const float* __restrict__ Wv,
                     const float* __restrict__ Wo,
                     float* __restrict__ proj_out,
                     float* __restrict__ attn_out)
{
    __shared__ float lds[LDS_FLOATS];

    const int tid = threadIdx.x;
    const int bn  = blockIdx.x;
    const int w   = tid >> 6;             // wave id 0..3 -> z-range [64w, 64w+64)
    const int l   = tid & 63;             // lane; owns rows 64j+l, j=0..3

    // ---- weights -> LDS ----
    lds[WQ_OFF + tid] = Wq[tid];
    lds[WK_OFF + tid] = Wk[tid];
    lds[WV_OFF + tid] = Wv[tid];
    lds[WO_OFF + tid] = Wo[tid];
    __syncthreads();

    const size_t inoff = (size_t)bn * NL_ * DM_;

    // ---- phase 1: per-row projections (thread t computes row t) ----
    {
        float rowbuf[16], acc[16];

        // Q row -> QP (padded stride 17)
        {
            const float4* p = (const float4*)(Q + inoff + (size_t)tid * DM_);
            #pragma unroll
            for (int i = 0; i < 4; ++i) {
                float4 t = p[i];
                rowbuf[4*i+0] = t.x; rowbuf[4*i+1] = t.y;
                rowbuf[4*i+2] = t.z; rowbuf[4*i+3] = t.w;
            }
            #pragma unroll
            for (int c = 0; c < 16; ++c) acc[c] = 0.f;
            #pragma unroll
            for (int i = 0; i < 16; ++i) {
                const float qi = rowbuf[i];
                #pragma unroll
                for (int c = 0; c < 16; ++c) acc[c] += qi * lds[WQ_OFF + i*16 + c];
            }
            #pragma unroll
            for (int c = 0; c < 16; ++c) lds[QP_OFF + tid*17 + c] = acc[c];
        }
        // K row -> KP (stride 16)
        {
            const float4* p = (const float4*)(K + inoff + (size_t)tid * DM_);
            #pragma unroll
            for (int i = 0; i < 4; ++i) {
                float4 t = p[i];
                rowbuf[4*i+0] = t.x; rowbuf[4*i+1] = t.y;
                rowbuf[4*i+2] = t.z; rowbuf[4*i+3] = t.w;
            }
            #pragma unroll
            for (int c = 0; c < 16; ++c) acc[c] = 0.f;
            #pragma unroll
            for (int i = 0; i < 16; ++i) {
                const float ki = rowbuf[i];
                #pragma unroll
                for (int c = 0; c < 16; ++c) acc[c] += ki * lds[WK_OFF + i*16 + c];
            }
            #pragma unroll
            for (int c = 0; c < 16; ++c) lds[KP_OFF + tid*16 + c] = acc[c];
        }
        // V row -> VP
        {
            const float4* p = (const float4*)(V + inoff + (size_t)tid * DM_);
            #pragma unroll
            for (int i = 0; i < 4; ++i) {
                float4 t = p[i];
                rowbuf[4*i+0] = t.x; rowbuf[4*i+1] = t.y;
                rowbuf[4*i+2] = t.z; rowbuf[4*i+3] = t.w;
            }
            #pragma unroll
            for (int c = 0; c < 16; ++c) acc[c] = 0.f;
            #pragma unroll
            for (int i = 0; i < 16; ++i) {
                const float vi = rowbuf[i];
                #pragma unroll
                for (int c = 0; c < 16; ++c) acc[c] += vi * lds[WV_OFF + i*16 + c];
            }
            #pragma unroll
            for (int c = 0; c < 16; ++c) lds[VP_OFF + tid*16 + c] = acc[c];
        }
    }
    __syncthreads();

    // ---- this lane's 4 Qp rows -> registers (stride-17: 2-way, free) ----
    float Qp[4][16];
    #pragma unroll
    for (int j = 0; j < 4; ++j) {
        const int row = 64*j + l;
        #pragma unroll
        for (int c = 0; c < 16; ++c) Qp[j][c] = lds[QP_OFF + row*17 + c];
    }

    float emb[4][16];
    #pragma unroll
    for (int j = 0; j < 4; ++j)
        #pragma unroll
        for (int c = 0; c < 16; ++c) emb[j][c] = 0.f;

    const int z0 = w * 64;
    float* aout = attn_out + (size_t)bn * NL_ * NL_;

    // ---- main loop: 4 store-batches of 16 columns each ----
    #pragma unroll 1
    for (int sb = 0; sb < 4; ++sb) {
        float atr[4][16];                 // 16-col staging (64 B/row, sector-complete)
        #pragma unroll
        for (int ii = 0; ii < 4; ++ii) {
            #pragma unroll
            for (int dz = 0; dz < 4; ++dz) {
                const int z = z0 + sb*16 + ii*4 + dz;
                // broadcast reads (wave-uniform address: conflict-free)
                const float4 k0 = *(const float4*)&lds[KP_OFF + z*16 + 0];
                const float4 k1 = *(const float4*)&lds[KP_OFF + z*16 + 4];
                const float4 k2 = *(const float4*)&lds[KP_OFF + z*16 + 8];
                const float4 k3 = *(const float4*)&lds[KP_OFF + z*16 + 12];
                const float4 v0 = *(const float4*)&lds[VP_OFF + z*16 + 0];
                const float4 v1 = *(const float4*)&lds[VP_OFF + z*16 + 4];
                const float4 v2 = *(const float4*)&lds[VP_OFF + z*16 + 8];
                const float4 v3 = *(const float4*)&lds[VP_OFF + z*16 + 12];
                #pragma unroll
                for (int j = 0; j < 4; ++j) {
                    float s0 = Qp[j][0]*k0.x + Qp[j][1]*k0.y + Qp[j][2]*k0.z + Qp[j][3]*k0.w
                             + Qp[j][4]*k1.x + Qp[j][5]*k1.y + Qp[j][6]*k1.z + Qp[j][7]*k1.w;
                    float s1 = Qp[j][8]*k2.x + Qp[j][9]*k2.y + Qp[j][10]*k2.z + Qp[j][11]*k2.w
                             + Qp[j][12]*k3.x + Qp[j][13]*k3.y + Qp[j][14]*k3.z + Qp[j][15]*k3.w;
                    s0 = fmaxf(s0, 0.f);
                    s1 = fmaxf(s1, 0.f);
                    atr[j][ii*4 + dz] = 0.5f * (s0 + s1);
                    emb[j][0]  += s0*v0.x; emb[j][1]  += s0*v0.y; emb[j][2]  += s0*v0.z; emb[j][3]  += s0*v0.w;
                    emb[j][4]  += s0*v1.x; emb[j][5]  += s0*v1.y; emb[j][6]  += s0*v1.z; emb[j][7]  += s0*v1.w;
                    emb[j][8]  += s1*v2.x; emb[j][9]  += s1*v2.y; emb[j][10] += s1*v2.z; emb[j][11] += s1*v2.w;
                    emb[j][12] += s1*v3.x; emb[j][13] += s1*v3.y; emb[j][14] += s1*v3.z; emb[j][15] += s1*v3.w;
                }
            }
        }
        // store: per row 64 B contiguous, 64-B aligned (4 back-to-back dwordx4
        // from one lane -> full sector coverage, L2 merges to one HBM writeback)
        #pragma unroll
        for (int j = 0; j < 4; ++j) {
            float4* dst = (float4*)&aout[(size_t)(64*j + l) * NL_ + z0 + sb*16];
            dst[0] = make_float4(atr[j][0],  atr[j][1],  atr[j][2],  atr[j][3]);
            dst[1] = make_float4(atr[j][4],  atr[j][5],  atr[j][6],  atr[j][7]);
            dst[2] = make_float4(atr[j][8],  atr[j][9],  atr[j][10], atr[j][11]);
            dst[3] = make_float4(atr[j][12], atr[j][13], atr[j][14], atr[j][15]);
        }
    }

    // ---- cross-wave emb reduction (z-split partials) ----
    __syncthreads();                      // QP/KP/VP dead from here
    if (w == 0) {
        #pragma unroll
        for (int j = 0; j < 4; ++j)
            #pragma unroll
            for (int c = 0; c < 16; ++c) lds[EMBA_OFF + (64*j+l)*17 + c] = emb[j][c];
    } else if (w == 1) {
        #pragma unroll
        for (int j = 0; j < 4; ++j)
            #pragma unroll
            for (int c = 0; c < 16; ++c) lds[EMBB_OFF + (64*j+l)*17 + c] = emb[j][c];
    }
    __syncthreads();
    if (w == 2) {
        #pragma unroll
        for (int j = 0; j < 4; ++j)
            #pragma unroll
            for (int c = 0; c < 16; ++c) lds[EMBA_OFF + (64*j+l)*17 + c] += emb[j][c];
    } else if (w == 3) {
        #pragma unroll
        for (int j = 0; j < 4; ++j)
            #pragma unroll
            for (int c = 0; c < 16; ++c) lds[EMBB_OFF + (64*j+l)*17 + c] += emb[j][c];
    }
    __syncthreads();

    // ---- output projection: thread t owns row t ----
    float e[16];
    #pragma unroll
    for (int c = 0; c < 16; ++c)
        e[c] = lds[EMBA_OFF + tid*17 + c] + lds[EMBB_OFF + tid*17 + c];

    float pr[16];
    #pragma unroll
    for (int o = 0; o < 16; ++o) pr[o] = 0.f;
    #pragma unroll
    for (int a = 0; a < 2; ++a) {
        #pragma unroll
        for (int m = 0; m < 8; ++m) {
            const float ev = e[a*8 + m];
            #pragma unroll
            for (int o = 0; o < 16; ++o) pr[o] += ev * lds[WO_OFF + m*32 + a*16 + o];
        }
    }
    float4* po = (float4*)(proj_out + (size_t)bn * NL_ * DOUT_ + (size_t)tid * DOUT_);
    po[0] = make_float4(pr[0],  pr[1],  pr[2],  pr[3]);
    po[1] = make_float4(pr[4],  pr[5],  pr[6],  pr[7]);
    po[2] = make_float4(pr[8],  pr[9],  pr[10], pr[11]);
    po[3] = make_float4(pr[12], pr[13], pr[14], pr[15]);
}

extern "C" void kernel_launch(void* const* d_in, const int* in_sizes, int n_in,
                              void* d_out, int out_size, void* d_ws, size_t ws_size,
                              hipStream_t stream) {
    const float* Q  = (const float*)d_in[0];
    const float* K  = (const float*)d_in[1];
    const float* V  = (const float*)d_in[2];
    const float* Wq = (const float*)d_in[3];
    const float* Wk = (const float*)d_in[4];
    const float* Wv = (const float*)d_in[5];
    const float* Wo = (const float*)d_in[6];

    float* proj = (float*)d_out;
    float* attn = (float*)d_out + PROJ_ELEMS;

    mha_relu_kernel<<<NBN, 256, 0, stream>>>(Q, K, V, Wq, Wk, Wv, Wo, proj, attn);
}